// Round 1
// baseline (160.038 us; speedup 1.0000x reference)
//
#include <hip/hip_runtime.h>
#include <hip/hip_bf16.h>
#include <math.h>

// SupCon loss, N=8192 D=128 fp32 in, scalar fp32 out.
// Round 4: (1) zero_kernel removed -- label histogram now built in finalize's
// LDS (1 block, 8192 shared atomics). (2) sim: A-fragments live in registers
// for the whole strip (read once from LDS, -16 ds_read_b128/wave/tile),
// B tiles ping-pong between two LDS buffers with ONE barrier per tile
// (stage into the free buffer right after the barrier; the epilogue covers
// the DMA latency). (3) epilogue specialized on wave-uniform `diag`: the
// self-exclusion cmp/cndmask chain only runs on the 64 diagonal tiles.

constexpr int N = 8192;
constexpr int D = 128;

typedef __attribute__((ext_vector_type(8))) short short8;  // 8 bf16 = 4 VGPRs
typedef __attribute__((ext_vector_type(4))) float f32x4;

__device__ __forceinline__ float fast_exp2(float x) {
#if __has_builtin(__builtin_amdgcn_exp2f)
    return __builtin_amdgcn_exp2f(x);
#else
    return __expf(x * 0.69314718056f);
#endif
}

__device__ __forceinline__ void gload_lds16(const void* g, void* s) {
    __builtin_amdgcn_global_load_lds(
        (const __attribute__((address_space(1))) unsigned int*)g,
        (__attribute__((address_space(3))) unsigned int*)s, 16, 0, 0);
}

// Stage one 128x128 bf16 tile (rows row0..row0+127) into LDS, source-side
// XOR swizzle so compute-side ds_read_b128 is conflict-free (dest must stay
// lane-contiguous per m104/m108).
__device__ __forceinline__ void stage_tile(const unsigned short* __restrict__ src,
                                           unsigned short* dst, int row0,
                                           int w, int lr, int lq) {
#pragma unroll
    for (int it = 0; it < 8; ++it) {
        int rbase = w * 32 + it * 4;
        int r = rbase + lr;
        int q = lq ^ (r & 7);
        gload_lds16(src + ((size_t)(row0 + r) * D + q * 8), dst + rbase * D);
    }
}

// ---------------- prep: bf16 rows scaled into log2 domain ------------------
__global__ void prep_kernel(const float* __restrict__ F,
                            unsigned short* __restrict__ Fb,
                            float* __restrict__ rowExp,
                            float* __restrict__ rowPos) {
    int row = blockIdx.x * 4 + (threadIdx.x >> 6);
    int l = threadIdx.x & 63;
    float2 v = ((const float2*)(F + (size_t)row * D))[l];
    float ss = v.x * v.x + v.y * v.y;
#pragma unroll
    for (int off = 32; off > 0; off >>= 1) ss += __shfl_xor(ss, off);
    float sc = sqrtf(14.4269504089f / ss);  // 10 * log2(e), folded
    __hip_bfloat16 hx = __float2bfloat16(v.x * sc);
    __hip_bfloat16 hy = __float2bfloat16(v.y * sc);
    ushort2 u;
    u.x = *(unsigned short*)&hx;
    u.y = *(unsigned short*)&hy;
    ((ushort2*)(Fb + (size_t)row * D))[l] = u;
    if (l == 0) {
        rowExp[row] = 0.0f;
        rowPos[row] = 0.0f;
    }
}

// ---------------- sim: triangular strips, MFMA 16x16x32 bf16 ----------------
__global__ __launch_bounds__(256, 2) void sim_kernel(
    const unsigned short* __restrict__ Fb, const int* __restrict__ labels,
    float* __restrict__ rowExp, float* __restrict__ rowPos) {
    __shared__ unsigned short B0[128 * D];  // 32 KB (A-tile staging, then B ping)
    __shared__ unsigned short B1[128 * D];  // 32 KB (B pong)

    // decode strip: 544 blocks = sum over q of 4 rows * (16-q) groups
    int bid = blockIdx.x, q = 0, base = 0;
    while (bid >= base + 4 * (16 - q)) { base += 4 * (16 - q); ++q; }
    int rem = bid - base, ng = 16 - q;
    int ti = 4 * q + rem / ng;
    int g = 15 - (rem % ng);        // diag-crossing strip (g==q) scheduled last
    int tjs = max(ti, 4 * g), tje = 4 * g + 3;
    const int i0 = ti * 128;

    const int t = threadIdx.x, w = t >> 6, l = t & 63;
    const int lr = l >> 4, lq = l & 15;     // staging lane split
    const int c = l & 15, quad = l >> 4;    // MFMA lane split
    const int wy = w >> 1, wx = w & 1;      // 64x64 quadrant per wave

    stage_tile(Fb, B0, i0, w, lr, lq);         // A tile (read to regs below)
    stage_tile(Fb, B1, tjs * 128, w, lr, lq);  // first B tile

    // row labels for this wave's rows (strip-constant)
    int li[4][4];
#pragma unroll
    for (int m = 0; m < 4; ++m)
#pragma unroll
        for (int r = 0; r < 4; ++r)
            li[m][r] = labels[i0 + wy * 64 + m * 16 + quad * 4 + r];

    __syncthreads();  // A in B0 and first B in B1 fully staged

    // A fragments for the whole strip: 16 short8 = 64 VGPRs, read ONCE.
    short8 Af[4][4];  // [kk][m]
#pragma unroll
    for (int kk = 0; kk < 4; ++kk) {
        int sl = (kk * 4 + quad) ^ (c & 7);  // undo swizzle (row&7 == c&7)
#pragma unroll
        for (int m = 0; m < 4; ++m)
            Af[kk][m] = *(const short8*)&B0[(wy * 64 + m * 16 + c) * D + sl * 8];
    }

    __syncthreads();  // all waves done reading B0 -> free for ping-pong

    float RE[4][4] = {}, RP[4][4] = {};  // row partials, carried across strip

    for (int tj = tjs; tj <= tje; ++tj) {
        const int it = tj - tjs;
        unsigned short* curB = (it & 1) ? B0 : B1;
        unsigned short* nxtB = (it & 1) ? B1 : B0;
        // overlap: DMA next B tile into the free buffer while we compute
        if (tj < tje) stage_tile(Fb, nxtB, (tj + 1) * 128, w, lr, lq);

        const int j0 = tj * 128;
        int lj[4];  // prefetch col labels; latency hides under ds_read+MFMA
#pragma unroll
        for (int n = 0; n < 4; ++n) lj[n] = labels[j0 + wx * 64 + n * 16 + c];

        f32x4 acc[4][4] = {};
#pragma unroll
        for (int kk = 0; kk < 4; ++kk) {
            short8 bf[4];
            int sl = (kk * 4 + quad) ^ (c & 7);
#pragma unroll
            for (int m = 0; m < 4; ++m)
                bf[m] = *(const short8*)&curB[(wx * 64 + m * 16 + c) * D + sl * 8];
#pragma unroll
            for (int m = 0; m < 4; ++m)
#pragma unroll
                for (int n = 0; n < 4; ++n)
                    acc[m][n] = __builtin_amdgcn_mfma_f32_16x16x32_bf16(
                        Af[kk][m], bf[n], acc[m][n], 0, 0, 0);
        }

        // ---- epilogue (registers only; overlaps the B DMA) ----
        if (tj == ti) {
            // diagonal tile: full block accumulated into rows only; exclude self
#pragma unroll
            for (int m = 0; m < 4; ++m) {
#pragma unroll
                for (int n = 0; n < 4; ++n) {
#pragma unroll
                    for (int r = 0; r < 4; ++r) {
                        float s2 = acc[m][n][r];
                        bool self = (wy * 64 + m * 16 + quad * 4 + r) ==
                                    (wx * 64 + n * 16 + c);
                        float e = self ? 0.0f : fast_exp2(s2);
                        float p = (!self && li[m][r] == lj[n]) ? s2 : 0.0f;
                        RE[m][r] += e;
                        RP[m][r] += p;
                    }
                }
            }
        } else {
            float ce[4] = {}, cp[4] = {};
#pragma unroll
            for (int m = 0; m < 4; ++m) {
#pragma unroll
                for (int n = 0; n < 4; ++n) {
#pragma unroll
                    for (int r = 0; r < 4; ++r) {
                        float s2 = acc[m][n][r];
                        float e = fast_exp2(s2);
                        float p = (li[m][r] == lj[n]) ? s2 : 0.0f;
                        RE[m][r] += e;
                        RP[m][r] += p;
                        ce[n] += e;
                        cp[n] += p;
                    }
                }
            }
            // transpose contribution: reduce down rows (quads) — 2 levels only
#pragma unroll
            for (int n = 0; n < 4; ++n) {
                ce[n] += __shfl_xor(ce[n], 16);
                ce[n] += __shfl_xor(ce[n], 32);
                cp[n] += __shfl_xor(cp[n], 16);
                cp[n] += __shfl_xor(cp[n], 32);
            }
            if (quad == 0) {
#pragma unroll
                for (int n = 0; n < 4; ++n) {
                    int gj = j0 + wx * 64 + n * 16 + c;
                    atomicAdd(&rowExp[gj], ce[n]);
                    atomicAdd(&rowPos[gj], cp[n]);
                }
            }
        }

        // one barrier per tile: drains this wave's DMA (vmcnt) and marks all
        // waves' reads of curB complete, so curB is free to stage into next.
        if (tj < tje) __syncthreads();
    }

    // strip end: row reduction across the 16 col-lanes (once per strip)
#pragma unroll
    for (int m = 0; m < 4; ++m)
#pragma unroll
        for (int r = 0; r < 4; ++r) {
#pragma unroll
            for (int off = 1; off < 16; off <<= 1) {
                RE[m][r] += __shfl_xor(RE[m][r], off);
                RP[m][r] += __shfl_xor(RP[m][r], off);
            }
        }
    if (c == 0) {
#pragma unroll
        for (int m = 0; m < 4; ++m)
#pragma unroll
            for (int r = 0; r < 4; ++r) {
                int gi = i0 + wy * 64 + m * 16 + quad * 4 + r;
                atomicAdd(&rowExp[gi], RE[m][r]);
                atomicAdd(&rowPos[gi], RP[m][r]);
            }
    }
}

// ---------------- finalize: loss = mean_i [ln(denom_i) - ln2*rowPos_i/cnt_i]
// Also builds the label histogram in LDS (replaces zero_kernel + prep atomics).
__global__ void finalize_kernel(const float* __restrict__ rowExp,
                                const float* __restrict__ rowPos,
                                const int* __restrict__ labels,
                                float* __restrict__ out) {
    __shared__ int hist[1024];
    __shared__ float ws16[16];
    int t = threadIdx.x;  // 1024 threads
    hist[t] = 0;
    __syncthreads();
    int lab[8];
#pragma unroll
    for (int k = 0; k < 8; ++k) {
        lab[k] = labels[t + 1024 * k];
        atomicAdd(&hist[lab[k]], 1);
    }
    __syncthreads();
    float a = 0.0f;
#pragma unroll
    for (int k = 0; k < 8; ++k) {
        int i = t + 1024 * k;
        int cnt = hist[lab[k]] - 1;
        if (cnt > 0)
            a += logf(rowExp[i] + 1e-9f) -
                 0.69314718056f * rowPos[i] / (float)cnt;
    }
#pragma unroll
    for (int off = 32; off > 0; off >>= 1) a += __shfl_xor(a, off);
    if ((t & 63) == 0) ws16[t >> 6] = a;
    __syncthreads();
    if (t == 0) {
        float s = 0.0f;
#pragma unroll
        for (int i = 0; i < 16; ++i) s += ws16[i];
        out[0] = s / (float)N;
    }
}

extern "C" void kernel_launch(void* const* d_in, const int* in_sizes, int n_in,
                              void* d_out, int out_size, void* d_ws, size_t ws_size,
                              hipStream_t stream) {
    const float* F      = (const float*)d_in[0];
    const int*   labels = (const int*)d_in[1];
    float* out = (float*)d_out;

    unsigned short* Fb = (unsigned short*)d_ws;     // N*D bf16 = 2 MB
    float* rowExp = (float*)(Fb + (size_t)N * D);   // N floats
    float* rowPos = rowExp + N;                     // N floats

    prep_kernel<<<N / 4, 256, 0, stream>>>(F, Fb, rowExp, rowPos);
    sim_kernel<<<544, 256, 0, stream>>>(Fb, labels, rowExp, rowPos);
    finalize_kernel<<<1, 1024, 0, stream>>>(rowExp, rowPos, labels, out);
}

// Round 2
// 115.470 us; speedup vs baseline: 1.3860x; 1.3860x over previous
//
#include <hip/hip_runtime.h>
#include <hip/hip_bf16.h>
#include <math.h>

// SupCon loss, N=8192 D=128 fp32 in, scalar fp32 out.
// Round 5: revert round-4's A-in-registers + one-barrier ping-pong (it spilled:
// WRITE_SIZE 101 MB of scratch, sim 97us). Back to the round-3 known-good sim
// structure (At+Bt, 2 barriers/tile, af re-read per tile). KEEP the two
// register-neutral round-4 wins: (a) zero_kernel removed -- label histogram
// built in finalize's LDS; (b) epilogue specialized on wave-uniform diag so the
// self-exclusion cmp/select chain only runs on the 64 diagonal tiles.

constexpr int N = 8192;
constexpr int D = 128;

typedef __attribute__((ext_vector_type(8))) short short8;  // 8 bf16 = 4 VGPRs
typedef __attribute__((ext_vector_type(4))) float f32x4;

__device__ __forceinline__ float fast_exp2(float x) {
#if __has_builtin(__builtin_amdgcn_exp2f)
    return __builtin_amdgcn_exp2f(x);
#else
    return __expf(x * 0.69314718056f);
#endif
}

__device__ __forceinline__ void gload_lds16(const void* g, void* s) {
    __builtin_amdgcn_global_load_lds(
        (const __attribute__((address_space(1))) unsigned int*)g,
        (__attribute__((address_space(3))) unsigned int*)s, 16, 0, 0);
}

// Stage one 128x128 bf16 tile (rows row0..row0+127) into LDS, source-side
// XOR swizzle so compute-side ds_read_b128 is conflict-free (dest must stay
// lane-contiguous per m104/m108).
__device__ __forceinline__ void stage_tile(const unsigned short* __restrict__ src,
                                           unsigned short* dst, int row0,
                                           int w, int lr, int lq) {
#pragma unroll
    for (int it = 0; it < 8; ++it) {
        int rbase = w * 32 + it * 4;
        int r = rbase + lr;
        int q = lq ^ (r & 7);
        gload_lds16(src + ((size_t)(row0 + r) * D + q * 8), dst + rbase * D);
    }
}

// ---------------- prep: bf16 rows scaled into log2 domain ------------------
__global__ void prep_kernel(const float* __restrict__ F,
                            unsigned short* __restrict__ Fb,
                            float* __restrict__ rowExp,
                            float* __restrict__ rowPos) {
    int row = blockIdx.x * 4 + (threadIdx.x >> 6);
    int l = threadIdx.x & 63;
    float2 v = ((const float2*)(F + (size_t)row * D))[l];
    float ss = v.x * v.x + v.y * v.y;
#pragma unroll
    for (int off = 32; off > 0; off >>= 1) ss += __shfl_xor(ss, off);
    float sc = sqrtf(14.4269504089f / ss);  // 10 * log2(e), folded
    __hip_bfloat16 hx = __float2bfloat16(v.x * sc);
    __hip_bfloat16 hy = __float2bfloat16(v.y * sc);
    ushort2 u;
    u.x = *(unsigned short*)&hx;
    u.y = *(unsigned short*)&hy;
    ((ushort2*)(Fb + (size_t)row * D))[l] = u;
    if (l == 0) {
        rowExp[row] = 0.0f;
        rowPos[row] = 0.0f;
    }
}

// ---------------- sim: triangular strips, MFMA 16x16x32 bf16 ----------------
__global__ __launch_bounds__(256, 2) void sim_kernel(
    const unsigned short* __restrict__ Fb, const int* __restrict__ labels,
    float* __restrict__ rowExp, float* __restrict__ rowPos) {
    __shared__ unsigned short At[128 * D];  // 32 KB
    __shared__ unsigned short Bt[128 * D];  // 32 KB

    // decode strip: 544 blocks = sum over q of 4 rows * (16-q) groups
    int bid = blockIdx.x, q = 0, base = 0;
    while (bid >= base + 4 * (16 - q)) { base += 4 * (16 - q); ++q; }
    int rem = bid - base, ng = 16 - q;
    int ti = 4 * q + rem / ng;
    int g = 15 - (rem % ng);        // diag-crossing strip (g==q) scheduled last
    int tjs = max(ti, 4 * g), tje = 4 * g + 3;
    const int i0 = ti * 128;

    const int t = threadIdx.x, w = t >> 6, l = t & 63;
    const int lr = l >> 4, lq = l & 15;     // staging lane split
    const int c = l & 15, quad = l >> 4;    // MFMA lane split
    const int wy = w >> 1, wx = w & 1;      // 64x64 quadrant per wave

    stage_tile(Fb, At, i0, w, lr, lq);
    stage_tile(Fb, Bt, tjs * 128, w, lr, lq);

    // row labels for this wave's rows (strip-constant)
    int li[4][4];
#pragma unroll
    for (int m = 0; m < 4; ++m)
#pragma unroll
        for (int r = 0; r < 4; ++r)
            li[m][r] = labels[i0 + wy * 64 + m * 16 + quad * 4 + r];

    float RE[4][4] = {}, RP[4][4] = {};  // row partials, carried across strip

    for (int tj = tjs; tj <= tje; ++tj) {
        __syncthreads();  // staging of Bt (and At on first iter) complete
        int j0 = tj * 128;
        f32x4 acc[4][4] = {};
#pragma unroll
        for (int kk = 0; kk < 4; ++kk) {
            short8 af[4], bf[4];
            int sl = (kk * 4 + quad) ^ (c & 7);  // undo swizzle (row&7 == c&7)
#pragma unroll
            for (int m = 0; m < 4; ++m) {
                af[m] = *(const short8*)&At[(wy * 64 + m * 16 + c) * D + sl * 8];
                bf[m] = *(const short8*)&Bt[(wx * 64 + m * 16 + c) * D + sl * 8];
            }
#pragma unroll
            for (int m = 0; m < 4; ++m)
#pragma unroll
                for (int n = 0; n < 4; ++n)
                    acc[m][n] = __builtin_amdgcn_mfma_f32_16x16x32_bf16(
                        af[m], bf[n], acc[m][n], 0, 0, 0);
        }
        __syncthreads();  // all waves done reading Bt
        if (tj < tje) stage_tile(Fb, Bt, (tj + 1) * 128, w, lr, lq);  // overlap DMA

        // ---- epilogue (registers only; overlaps the B DMA) ----
        int lj[4];
#pragma unroll
        for (int n = 0; n < 4; ++n) lj[n] = labels[j0 + wx * 64 + n * 16 + c];

        if (tj == ti) {
            // diagonal tile: rows only; exclude self-comparisons
#pragma unroll
            for (int m = 0; m < 4; ++m) {
#pragma unroll
                for (int n = 0; n < 4; ++n) {
#pragma unroll
                    for (int r = 0; r < 4; ++r) {
                        float s2 = acc[m][n][r];
                        bool self = (wy * 64 + m * 16 + quad * 4 + r) ==
                                    (wx * 64 + n * 16 + c);
                        float e = self ? 0.0f : fast_exp2(s2);
                        float p = (!self && li[m][r] == lj[n]) ? s2 : 0.0f;
                        RE[m][r] += e;
                        RP[m][r] += p;
                    }
                }
            }
        } else {
            float ce[4] = {}, cp[4] = {};
#pragma unroll
            for (int m = 0; m < 4; ++m) {
#pragma unroll
                for (int n = 0; n < 4; ++n) {
#pragma unroll
                    for (int r = 0; r < 4; ++r) {
                        float s2 = acc[m][n][r];
                        float e = fast_exp2(s2);
                        float p = (li[m][r] == lj[n]) ? s2 : 0.0f;
                        RE[m][r] += e;
                        RP[m][r] += p;
                        ce[n] += e;
                        cp[n] += p;
                    }
                }
            }
            // transpose contribution: reduce down rows (quads) — 2 levels only
#pragma unroll
            for (int n = 0; n < 4; ++n) {
                ce[n] += __shfl_xor(ce[n], 16);
                ce[n] += __shfl_xor(ce[n], 32);
                cp[n] += __shfl_xor(cp[n], 16);
                cp[n] += __shfl_xor(cp[n], 32);
            }
            if (quad == 0) {
#pragma unroll
                for (int n = 0; n < 4; ++n) {
                    int gj = j0 + wx * 64 + n * 16 + c;
                    atomicAdd(&rowExp[gj], ce[n]);
                    atomicAdd(&rowPos[gj], cp[n]);
                }
            }
        }
    }

    // strip end: row reduction across the 16 col-lanes (once per strip)
#pragma unroll
    for (int m = 0; m < 4; ++m)
#pragma unroll
        for (int r = 0; r < 4; ++r) {
#pragma unroll
            for (int off = 1; off < 16; off <<= 1) {
                RE[m][r] += __shfl_xor(RE[m][r], off);
                RP[m][r] += __shfl_xor(RP[m][r], off);
            }
        }
    if (c == 0) {
#pragma unroll
        for (int m = 0; m < 4; ++m)
#pragma unroll
            for (int r = 0; r < 4; ++r) {
                int gi = i0 + wy * 64 + m * 16 + quad * 4 + r;
                atomicAdd(&rowExp[gi], RE[m][r]);
                atomicAdd(&rowPos[gi], RP[m][r]);
            }
    }
}

// ---------------- finalize: loss = mean_i [ln(denom_i) - ln2*rowPos_i/cnt_i]
// Also builds the label histogram in LDS (replaces zero_kernel + prep atomics).
__global__ void finalize_kernel(const float* __restrict__ rowExp,
                                const float* __restrict__ rowPos,
                                const int* __restrict__ labels,
                                float* __restrict__ out) {
    __shared__ int hist[1024];
    __shared__ float ws16[16];
    int t = threadIdx.x;  // 1024 threads
    hist[t] = 0;
    __syncthreads();
    int lab[8];
#pragma unroll
    for (int k = 0; k < 8; ++k) {
        lab[k] = labels[t + 1024 * k];
        atomicAdd(&hist[lab[k]], 1);
    }
    __syncthreads();
    float a = 0.0f;
#pragma unroll
    for (int k = 0; k < 8; ++k) {
        int i = t + 1024 * k;
        int cnt = hist[lab[k]] - 1;
        if (cnt > 0)
            a += logf(rowExp[i] + 1e-9f) -
                 0.69314718056f * rowPos[i] / (float)cnt;
    }
#pragma unroll
    for (int off = 32; off > 0; off >>= 1) a += __shfl_xor(a, off);
    if ((t & 63) == 0) ws16[t >> 6] = a;
    __syncthreads();
    if (t == 0) {
        float s = 0.0f;
#pragma unroll
        for (int i = 0; i < 16; ++i) s += ws16[i];
        out[0] = s / (float)N;
    }
}

extern "C" void kernel_launch(void* const* d_in, const int* in_sizes, int n_in,
                              void* d_out, int out_size, void* d_ws, size_t ws_size,
                              hipStream_t stream) {
    const float* F      = (const float*)d_in[0];
    const int*   labels = (const int*)d_in[1];
    float* out = (float*)d_out;

    unsigned short* Fb = (unsigned short*)d_ws;     // N*D bf16 = 2 MB
    float* rowExp = (float*)(Fb + (size_t)N * D);   // N floats
    float* rowPos = rowExp + N;                     // N floats

    prep_kernel<<<N / 4, 256, 0, stream>>>(F, Fb, rowExp, rowPos);
    sim_kernel<<<544, 256, 0, stream>>>(Fb, labels, rowExp, rowPos);
    finalize_kernel<<<1, 1024, 0, stream>>>(rowExp, rowPos, labels, out);
}

// Round 3
// 106.940 us; speedup vs baseline: 1.4965x; 1.0798x over previous
//
#include <hip/hip_runtime.h>
#include <hip/hip_bf16.h>
#include <math.h>

// SupCon loss, N=8192 D=128 fp32 in, scalar fp32 out.
// Round 6: sim is atomic-bound, not compute-bound (WRITE_SIZE 44 MB = 1.3M
// device-scope atomics at ~32B coherence traffic each; they sit inside the
// per-tile loop and get drained by every barrier's vmcnt(0)). Switch from
// triangular strips to the FULL matrix: 1024 blocks = 64 row-tiles x 16
// column groups of 4 tiles. MFMA work doubles (5% -> 10% util, fine) but the
// epilogue is row-only (no transpose/column pass, no shuffles, no per-tile
// atomics). Atomics now happen ONCE per block at strip end (131K total, 10x
// fewer, off the barrier-drain path). Perfect load balance: 1024 uniform
// strips = exactly 2 resident rounds of 2 blocks/CU. Epilogue kept in the
// round-0 known-good unified form (self = diag && eq, predicated).

constexpr int N = 8192;
constexpr int D = 128;

typedef __attribute__((ext_vector_type(8))) short short8;  // 8 bf16 = 4 VGPRs
typedef __attribute__((ext_vector_type(4))) float f32x4;

__device__ __forceinline__ float fast_exp2(float x) {
#if __has_builtin(__builtin_amdgcn_exp2f)
    return __builtin_amdgcn_exp2f(x);
#else
    return __expf(x * 0.69314718056f);
#endif
}

__device__ __forceinline__ void gload_lds16(const void* g, void* s) {
    __builtin_amdgcn_global_load_lds(
        (const __attribute__((address_space(1))) unsigned int*)g,
        (__attribute__((address_space(3))) unsigned int*)s, 16, 0, 0);
}

// Stage one 128x128 bf16 tile (rows row0..row0+127) into LDS, source-side
// XOR swizzle so compute-side ds_read_b128 is conflict-free (dest must stay
// lane-contiguous per m104/m108).
__device__ __forceinline__ void stage_tile(const unsigned short* __restrict__ src,
                                           unsigned short* dst, int row0,
                                           int w, int lr, int lq) {
#pragma unroll
    for (int it = 0; it < 8; ++it) {
        int rbase = w * 32 + it * 4;
        int r = rbase + lr;
        int q = lq ^ (r & 7);
        gload_lds16(src + ((size_t)(row0 + r) * D + q * 8), dst + rbase * D);
    }
}

// ---------------- prep: bf16 rows scaled into log2 domain ------------------
__global__ void prep_kernel(const float* __restrict__ F,
                            unsigned short* __restrict__ Fb,
                            float* __restrict__ rowExp,
                            float* __restrict__ rowPos) {
    int row = blockIdx.x * 4 + (threadIdx.x >> 6);
    int l = threadIdx.x & 63;
    float2 v = ((const float2*)(F + (size_t)row * D))[l];
    float ss = v.x * v.x + v.y * v.y;
#pragma unroll
    for (int off = 32; off > 0; off >>= 1) ss += __shfl_xor(ss, off);
    float sc = sqrtf(14.4269504089f / ss);  // 10 * log2(e), folded
    __hip_bfloat16 hx = __float2bfloat16(v.x * sc);
    __hip_bfloat16 hy = __float2bfloat16(v.y * sc);
    ushort2 u;
    u.x = *(unsigned short*)&hx;
    u.y = *(unsigned short*)&hy;
    ((ushort2*)(Fb + (size_t)row * D))[l] = u;
    if (l == 0) {
        rowExp[row] = 0.0f;
        rowPos[row] = 0.0f;
    }
}

// ---------------- sim: full matrix, MFMA 16x16x32 bf16 ----------------------
// Block (ti, g): A-tile ti staged once; B-tiles tj in [4g, 4g+3].
// Row partials only; reduced across lanes and atomically added ONCE per block.
__global__ __launch_bounds__(256, 2) void sim_kernel(
    const unsigned short* __restrict__ Fb, const int* __restrict__ labels,
    float* __restrict__ rowExp, float* __restrict__ rowPos) {
    __shared__ unsigned short At[128 * D];  // 32 KB
    __shared__ unsigned short Bt[128 * D];  // 32 KB

    const int ti = blockIdx.x >> 4;   // 64 row tiles
    const int g  = blockIdx.x & 15;   // 16 column groups
    const int tjs = g * 4;
    const int i0 = ti * 128;

    const int t = threadIdx.x, w = t >> 6, l = t & 63;
    const int lr = l >> 4, lq = l & 15;     // staging lane split
    const int c = l & 15, quad = l >> 4;    // MFMA lane split
    const int wy = w >> 1, wx = w & 1;      // 64x64 quadrant per wave

    stage_tile(Fb, At, i0, w, lr, lq);
    stage_tile(Fb, Bt, tjs * 128, w, lr, lq);

    // row labels for this wave's rows (strip-constant)
    int li[4][4];
#pragma unroll
    for (int m = 0; m < 4; ++m)
#pragma unroll
        for (int r = 0; r < 4; ++r)
            li[m][r] = labels[i0 + wy * 64 + m * 16 + quad * 4 + r];

    float RE[4][4] = {}, RP[4][4] = {};  // row partials, carried across strip

    for (int tj = tjs; tj < tjs + 4; ++tj) {
        __syncthreads();  // staging of Bt (and At on first iter) complete
        const int j0 = tj * 128;
        int lj[4];  // issue label loads early; latency hides under ds_read+MFMA
#pragma unroll
        for (int n = 0; n < 4; ++n) lj[n] = labels[j0 + wx * 64 + n * 16 + c];

        f32x4 acc[4][4] = {};
#pragma unroll
        for (int kk = 0; kk < 4; ++kk) {
            short8 af[4], bf[4];
            int sl = (kk * 4 + quad) ^ (c & 7);  // undo swizzle (row&7 == c&7)
#pragma unroll
            for (int m = 0; m < 4; ++m) {
                af[m] = *(const short8*)&At[(wy * 64 + m * 16 + c) * D + sl * 8];
                bf[m] = *(const short8*)&Bt[(wx * 64 + m * 16 + c) * D + sl * 8];
            }
#pragma unroll
            for (int m = 0; m < 4; ++m)
#pragma unroll
                for (int n = 0; n < 4; ++n)
                    acc[m][n] = __builtin_amdgcn_mfma_f32_16x16x32_bf16(
                        af[m], bf[n], acc[m][n], 0, 0, 0);
        }
        __syncthreads();  // all waves done reading Bt
        if (tj < tjs + 3) stage_tile(Fb, Bt, (tj + 1) * 128, w, lr, lq);

        // ---- row-only epilogue (registers only; overlaps the B DMA) ----
        const bool diag = (tj == ti);
#pragma unroll
        for (int m = 0; m < 4; ++m) {
#pragma unroll
            for (int n = 0; n < 4; ++n) {
#pragma unroll
                for (int r = 0; r < 4; ++r) {
                    float s2 = acc[m][n][r];
                    bool self = diag && ((wy * 64 + m * 16 + quad * 4 + r) ==
                                         (wx * 64 + n * 16 + c));
                    float e = self ? 0.0f : fast_exp2(s2);
                    float p = (!self && li[m][r] == lj[n]) ? s2 : 0.0f;
                    RE[m][r] += e;
                    RP[m][r] += p;
                }
            }
        }
    }

    // strip end: row reduction across the 16 col-lanes (once per block),
    // then the ONLY global atomics this kernel issues.
#pragma unroll
    for (int m = 0; m < 4; ++m)
#pragma unroll
        for (int r = 0; r < 4; ++r) {
#pragma unroll
            for (int off = 1; off < 16; off <<= 1) {
                RE[m][r] += __shfl_xor(RE[m][r], off);
                RP[m][r] += __shfl_xor(RP[m][r], off);
            }
        }
    if (c == 0) {
#pragma unroll
        for (int m = 0; m < 4; ++m)
#pragma unroll
            for (int r = 0; r < 4; ++r) {
                int gi = i0 + wy * 64 + m * 16 + quad * 4 + r;
                atomicAdd(&rowExp[gi], RE[m][r]);
                atomicAdd(&rowPos[gi], RP[m][r]);
            }
    }
}

// ---------------- finalize: loss = mean_i [ln(denom_i) - ln2*rowPos_i/cnt_i]
// Also builds the label histogram in LDS.
__global__ void finalize_kernel(const float* __restrict__ rowExp,
                                const float* __restrict__ rowPos,
                                const int* __restrict__ labels,
                                float* __restrict__ out) {
    __shared__ int hist[1024];
    __shared__ float ws16[16];
    int t = threadIdx.x;  // 1024 threads
    hist[t] = 0;
    __syncthreads();
    int lab[8];
#pragma unroll
    for (int k = 0; k < 8; ++k) {
        lab[k] = labels[t + 1024 * k];
        atomicAdd(&hist[lab[k]], 1);
    }
    __syncthreads();
    float a = 0.0f;
#pragma unroll
    for (int k = 0; k < 8; ++k) {
        int i = t + 1024 * k;
        int cnt = hist[lab[k]] - 1;
        if (cnt > 0)
            a += logf(rowExp[i] + 1e-9f) -
                 0.69314718056f * rowPos[i] / (float)cnt;
    }
#pragma unroll
    for (int off = 32; off > 0; off >>= 1) a += __shfl_xor(a, off);
    if ((t & 63) == 0) ws16[t >> 6] = a;
    __syncthreads();
    if (t == 0) {
        float s = 0.0f;
#pragma unroll
        for (int i = 0; i < 16; ++i) s += ws16[i];
        out[0] = s / (float)N;
    }
}

extern "C" void kernel_launch(void* const* d_in, const int* in_sizes, int n_in,
                              void* d_out, int out_size, void* d_ws, size_t ws_size,
                              hipStream_t stream) {
    const float* F      = (const float*)d_in[0];
    const int*   labels = (const int*)d_in[1];
    float* out = (float*)d_out;

    unsigned short* Fb = (unsigned short*)d_ws;     // N*D bf16 = 2 MB
    float* rowExp = (float*)(Fb + (size_t)N * D);   // N floats
    float* rowPos = rowExp + N;                     // N floats

    prep_kernel<<<N / 4, 256, 0, stream>>>(F, Fb, rowExp, rowPos);
    sim_kernel<<<64 * 16, 256, 0, stream>>>(Fb, labels, rowExp, rowPos);
    finalize_kernel<<<1, 1024, 0, stream>>>(rowExp, rowPos, labels, out);
}

// Round 4
// 106.853 us; speedup vs baseline: 1.4977x; 1.0008x over previous
//
#include <hip/hip_runtime.h>
#include <hip/hip_bf16.h>
#include <math.h>

// SupCon loss, N=8192 D=128 fp32 in, scalar fp32 out.
// Round 7: sim was phase-serialization-bound (barrier -> LDS phase -> barrier ->
// epilogue at only 8 waves/CU; LDS reads already at the b128 floor). Fb is 2 MB
// = L2-resident on every XCD (FETCH 8.4 MB), so LDS staging is pure overhead.
// This version has NO LDS and NO barriers in sim: prep writes Fb in a
// fragment-major layout  FbP[rho][chi][row16][16B]  (rho=row>>4, chi=k>>3), so
// one MFMA fragment = lane l reading 16B at rho*4096 + kk*1024 + l*16 -- a
// contiguous, perfectly-coalesced 1KB wave load served by L2. A-fragments are
// loaded once per block into registers (64 VGPR); B-fragments stream per
// kk-step. Waves free-run; latency hides under the co-resident wave.

constexpr int N = 8192;
constexpr int D = 128;

typedef __attribute__((ext_vector_type(8))) short short8;  // 8 bf16 = 4 VGPRs
typedef __attribute__((ext_vector_type(4))) float f32x4;

__device__ __forceinline__ float fast_exp2(float x) {
#if __has_builtin(__builtin_amdgcn_exp2f)
    return __builtin_amdgcn_exp2f(x);
#else
    return __expf(x * 0.69314718056f);
#endif
}

// ---------------- prep: bf16 rows scaled into log2 domain, fragment layout --
// FbP uint index for element pair (row, k=2l): (row>>4)*1024 + (l>>2)*64 +
// (row&15)*4 + (l&3). Chunk chi = l>>2 holds k = 8*chi .. 8*chi+7 in order.
__global__ void prep_kernel(const float* __restrict__ F,
                            unsigned int* __restrict__ FbP,
                            float* __restrict__ rowExp,
                            float* __restrict__ rowPos) {
    int row = blockIdx.x * 4 + (threadIdx.x >> 6);
    int l = threadIdx.x & 63;
    float2 v = ((const float2*)(F + (size_t)row * D))[l];
    float ss = v.x * v.x + v.y * v.y;
#pragma unroll
    for (int off = 32; off > 0; off >>= 1) ss += __shfl_xor(ss, off);
    float sc = sqrtf(14.4269504089f / ss);  // 10 * log2(e), folded
    __hip_bfloat16 hx = __float2bfloat16(v.x * sc);
    __hip_bfloat16 hy = __float2bfloat16(v.y * sc);
    unsigned int ux = *(unsigned short*)&hx;
    unsigned int uy = *(unsigned short*)&hy;
    unsigned int idx = ((unsigned)(row >> 4) << 10) | ((unsigned)(l >> 2) << 6) |
                       ((unsigned)(row & 15) << 2) | (unsigned)(l & 3);
    FbP[idx] = ux | (uy << 16);
    if (l == 0) {
        rowExp[row] = 0.0f;
        rowPos[row] = 0.0f;
    }
}

// ---------------- sim: full matrix, MFMA 16x16x32 bf16, no LDS, no barriers -
// Block (ti, g): A-frags for row-tile ti loaded once to registers; B-tiles
// tj in [4g, 4g+3] streamed from L2. Row partials only; one atomic batch at
// block end.
__global__ __launch_bounds__(256, 2) void sim_kernel(
    const short8* __restrict__ P, const int* __restrict__ labels,
    float* __restrict__ rowExp, float* __restrict__ rowPos) {
    const int ti = blockIdx.x >> 4;   // 64 row tiles
    const int g  = blockIdx.x & 15;   // 16 column groups
    const int tjs = g * 4;
    const int i0 = ti * 128;

    const int t = threadIdx.x, w = t >> 6, l = t & 63;
    const int c = l & 15, quad = l >> 4;    // MFMA lane split
    const int wy = w >> 1, wx = w & 1;      // 64x64 quadrant per wave

    // A fragments for the whole strip: 16 x 1KB coalesced loads, 64 VGPR.
    // P is in 16B units: block (rho, kk) starts at rho*256 + kk*64, + lane.
    short8 Af[4][4];  // [kk][m]
#pragma unroll
    for (int kk = 0; kk < 4; ++kk)
#pragma unroll
        for (int m = 0; m < 4; ++m)
            Af[kk][m] = P[(ti * 8 + wy * 4 + m) * 256 + kk * 64 + l];

    // row labels for this wave's rows (strip-constant)
    int li[4][4];
#pragma unroll
    for (int m = 0; m < 4; ++m)
#pragma unroll
        for (int r = 0; r < 4; ++r)
            li[m][r] = labels[i0 + wy * 64 + m * 16 + quad * 4 + r];

    float RE[4][4] = {}, RP[4][4] = {};  // row partials, carried across strip

    for (int tj = tjs; tj < tjs + 4; ++tj) {
        const int j0 = tj * 128;
        int lj[4];
#pragma unroll
        for (int n = 0; n < 4; ++n) lj[n] = labels[j0 + wx * 64 + n * 16 + c];

        f32x4 acc[4][4] = {};
#pragma unroll
        for (int kk = 0; kk < 4; ++kk) {
            short8 bf[4];
#pragma unroll
            for (int n = 0; n < 4; ++n)
                bf[n] = P[(tj * 8 + wx * 4 + n) * 256 + kk * 64 + l];
#pragma unroll
            for (int m = 0; m < 4; ++m)
#pragma unroll
                for (int n = 0; n < 4; ++n)
                    acc[m][n] = __builtin_amdgcn_mfma_f32_16x16x32_bf16(
                        Af[kk][m], bf[n], acc[m][n], 0, 0, 0);
        }

        // ---- row-only epilogue (registers only) ----
        const bool diag = (tj == ti);
#pragma unroll
        for (int m = 0; m < 4; ++m) {
#pragma unroll
            for (int n = 0; n < 4; ++n) {
#pragma unroll
                for (int r = 0; r < 4; ++r) {
                    float s2 = acc[m][n][r];
                    bool self = diag && ((wy * 64 + m * 16 + quad * 4 + r) ==
                                         (wx * 64 + n * 16 + c));
                    float e = self ? 0.0f : fast_exp2(s2);
                    float p = (!self && li[m][r] == lj[n]) ? s2 : 0.0f;
                    RE[m][r] += e;
                    RP[m][r] += p;
                }
            }
        }
    }

    // strip end: row reduction across the 16 col-lanes (once per block),
    // then the ONLY global atomics this kernel issues.
#pragma unroll
    for (int m = 0; m < 4; ++m)
#pragma unroll
        for (int r = 0; r < 4; ++r) {
#pragma unroll
            for (int off = 1; off < 16; off <<= 1) {
                RE[m][r] += __shfl_xor(RE[m][r], off);
                RP[m][r] += __shfl_xor(RP[m][r], off);
            }
        }
    if (c == 0) {
#pragma unroll
        for (int m = 0; m < 4; ++m)
#pragma unroll
            for (int r = 0; r < 4; ++r) {
                int gi = i0 + wy * 64 + m * 16 + quad * 4 + r;
                atomicAdd(&rowExp[gi], RE[m][r]);
                atomicAdd(&rowPos[gi], RP[m][r]);
            }
    }
}

// ---------------- finalize: loss = mean_i [ln(denom_i) - ln2*rowPos_i/cnt_i]
// Also builds the label histogram in LDS.
__global__ void finalize_kernel(const float* __restrict__ rowExp,
                                const float* __restrict__ rowPos,
                                const int* __restrict__ labels,
                                float* __restrict__ out) {
    __shared__ int hist[1024];
    __shared__ float ws16[16];
    int t = threadIdx.x;  // 1024 threads
    hist[t] = 0;
    __syncthreads();
    int lab[8];
#pragma unroll
    for (int k = 0; k < 8; ++k) {
        lab[k] = labels[t + 1024 * k];
        atomicAdd(&hist[lab[k]], 1);
    }
    __syncthreads();
    float a = 0.0f;
#pragma unroll
    for (int k = 0; k < 8; ++k) {
        int i = t + 1024 * k;
        int cnt = hist[lab[k]] - 1;
        if (cnt > 0)
            a += logf(rowExp[i] + 1e-9f) -
                 0.69314718056f * rowPos[i] / (float)cnt;
    }
#pragma unroll
    for (int off = 32; off > 0; off >>= 1) a += __shfl_xor(a, off);
    if ((t & 63) == 0) ws16[t >> 6] = a;
    __syncthreads();
    if (t == 0) {
        float s = 0.0f;
#pragma unroll
        for (int i = 0; i < 16; ++i) s += ws16[i];
        out[0] = s / (float)N;
    }
}

extern "C" void kernel_launch(void* const* d_in, const int* in_sizes, int n_in,
                              void* d_out, int out_size, void* d_ws, size_t ws_size,
                              hipStream_t stream) {
    const float* F      = (const float*)d_in[0];
    const int*   labels = (const int*)d_in[1];
    float* out = (float*)d_out;

    unsigned int* FbP = (unsigned int*)d_ws;            // N*D bf16 = 2 MB
    float* rowExp = (float*)((unsigned short*)d_ws + (size_t)N * D);  // N floats
    float* rowPos = rowExp + N;                          // N floats

    prep_kernel<<<N / 4, 256, 0, stream>>>(F, FbP, rowExp, rowPos);
    sim_kernel<<<64 * 16, 256, 0, stream>>>((const short8*)FbP, labels, rowExp,
                                            rowPos);
    finalize_kernel<<<1, 1024, 0, stream>>>(rowExp, rowPos, labels, out);
}

// Round 5
// 105.998 us; speedup vs baseline: 1.5098x; 1.0081x over previous
//
#include <hip/hip_runtime.h>
#include <hip/hip_bf16.h>
#include <math.h>

// SupCon loss, N=8192 D=128 fp32 in, scalar fp32 out.
// Round 8: Theory = sim is INSTRUCTION-FETCH bound, not data-path bound.
// Evidence: three structurally different sims (triangular, LDS-tiled, no-LDS)
// all ~46-56us with every pipe <30% busy; fully-unrolled strip = ~40KB code
// > 32KB I$; the 2x-code R1 version ran exactly 2x slower; cold-I$ first
// dispatches 1.4-2x slower. Fix: (a) tj loop NOT unrolled (#pragma unroll 1)
// -> ~4KB body, I$-resident; (b) epilogue thinned to 5 insts/element
// (exp, add, cmp, cndmask, add) by replacing per-element self-exclusion with
// acc-poisoning: in the diag tile, the 4 self elements per lane (wy==wx,
// c==quad*4+r) are set to -50 before the epilogue (exp2(-50)=9e-16 vanishes;
// the -50 injected into the positive-sum is added back exactly before the
// atomics). Data path unchanged from round 7 (fragment-major Fb in L2, no LDS,
// no barriers, A-frags in registers, one atomic batch per block).

constexpr int N = 8192;
constexpr int D = 128;

typedef __attribute__((ext_vector_type(8))) short short8;  // 8 bf16 = 4 VGPRs
typedef __attribute__((ext_vector_type(4))) float f32x4;

constexpr float SELF_POISON = -50.0f;  // exp2(-50) ~ 9e-16; |s2| <= 14.43 real

__device__ __forceinline__ float fast_exp2(float x) {
#if __has_builtin(__builtin_amdgcn_exp2f)
    return __builtin_amdgcn_exp2f(x);
#else
    return __expf(x * 0.69314718056f);
#endif
}

// ---------------- prep: bf16 rows scaled into log2 domain, fragment layout --
// FbP uint index for element pair (row, k=2l): (row>>4)*1024 + (l>>2)*64 +
// (row&15)*4 + (l&3). Chunk chi = l>>2 holds k = 8*chi .. 8*chi+7 in order.
__global__ void prep_kernel(const float* __restrict__ F,
                            unsigned int* __restrict__ FbP,
                            float* __restrict__ rowExp,
                            float* __restrict__ rowPos) {
    int row = blockIdx.x * 4 + (threadIdx.x >> 6);
    int l = threadIdx.x & 63;
    float2 v = ((const float2*)(F + (size_t)row * D))[l];
    float ss = v.x * v.x + v.y * v.y;
#pragma unroll
    for (int off = 32; off > 0; off >>= 1) ss += __shfl_xor(ss, off);
    float sc = sqrtf(14.4269504089f / ss);  // 10 * log2(e), folded
    __hip_bfloat16 hx = __float2bfloat16(v.x * sc);
    __hip_bfloat16 hy = __float2bfloat16(v.y * sc);
    unsigned int ux = *(unsigned short*)&hx;
    unsigned int uy = *(unsigned short*)&hy;
    unsigned int idx = ((unsigned)(row >> 4) << 10) | ((unsigned)(l >> 2) << 6) |
                       ((unsigned)(row & 15) << 2) | (unsigned)(l & 3);
    FbP[idx] = ux | (uy << 16);
    if (l == 0) {
        rowExp[row] = 0.0f;
        rowPos[row] = 0.0f;
    }
}

// ---------------- sim: full matrix, MFMA 16x16x32 bf16, no LDS, no barriers -
__global__ __launch_bounds__(256, 2) void sim_kernel(
    const short8* __restrict__ P, const int* __restrict__ labels,
    float* __restrict__ rowExp, float* __restrict__ rowPos) {
    const int ti = blockIdx.x >> 4;   // 64 row tiles
    const int g  = blockIdx.x & 15;   // 16 column groups
    const int tjs = g * 4;
    const int i0 = ti * 128;

    const int t = threadIdx.x, w = t >> 6, l = t & 63;
    const int c = l & 15, quad = l >> 4;    // MFMA lane split
    const int wy = w >> 1, wx = w & 1;      // 64x64 quadrant per wave

    // A fragments for the whole strip: 16 x 1KB coalesced loads, 64 VGPR.
    short8 Af[4][4];  // [kk][m]
#pragma unroll
    for (int kk = 0; kk < 4; ++kk)
#pragma unroll
        for (int m = 0; m < 4; ++m)
            Af[kk][m] = P[(ti * 8 + wy * 4 + m) * 256 + kk * 64 + l];

    // row labels for this wave's rows (strip-constant)
    int li[4][4];
#pragma unroll
    for (int m = 0; m < 4; ++m)
#pragma unroll
        for (int r = 0; r < 4; ++r)
            li[m][r] = labels[i0 + wy * 64 + m * 16 + quad * 4 + r];

    const bool selfQuad = (quad == (c >> 2));  // lane may hold self elements

    float RE[4][4] = {}, RP[4][4] = {};  // row partials, carried across strip

#pragma unroll 1
    for (int tj = tjs; tj < tjs + 4; ++tj) {
        const int j0 = tj * 128;
        int lj[4];
#pragma unroll
        for (int n = 0; n < 4; ++n) lj[n] = labels[j0 + wx * 64 + n * 16 + c];

        f32x4 acc[4][4] = {};
#pragma unroll
        for (int kk = 0; kk < 4; ++kk) {
            short8 bf[4];
#pragma unroll
            for (int n = 0; n < 4; ++n)
                bf[n] = P[(tj * 8 + wx * 4 + n) * 256 + kk * 64 + l];
#pragma unroll
            for (int m = 0; m < 4; ++m)
#pragma unroll
                for (int n = 0; n < 4; ++n)
                    acc[m][n] = __builtin_amdgcn_mfma_f32_16x16x32_bf16(
                        Af[kk][m], bf[n], acc[m][n], 0, 0, 0);
        }

        // Diagonal tile: poison the self elements so the clean epilogue
        // naturally zeroes them (exp2(-50) ~ 0; the -50 entering RP is added
        // back exactly before the atomics). Wave-uniform branch; only waves
        // wy==wx of the 64 diag blocks ever take it.
        if (tj == ti && wy == wx) {
#pragma unroll
            for (int m = 0; m < 4; ++m)
#pragma unroll
                for (int r = 0; r < 4; ++r) {
                    bool cond = selfQuad && (r == (c & 3));
                    acc[m][m][r] = cond ? SELF_POISON : acc[m][m][r];
                }
        }

        // ---- minimal row-only epilogue: 5 insts per element ----
#pragma unroll
        for (int m = 0; m < 4; ++m) {
#pragma unroll
            for (int n = 0; n < 4; ++n) {
#pragma unroll
                for (int r = 0; r < 4; ++r) {
                    float s2 = acc[m][n][r];
                    RE[m][r] += fast_exp2(s2);
                    RP[m][r] += (li[m][r] == lj[n]) ? s2 : 0.0f;
                }
            }
        }
    }

    // strip end: row reduction across the 16 col-lanes (once per block),
    // then the ONLY global atomics this kernel issues.
#pragma unroll
    for (int m = 0; m < 4; ++m)
#pragma unroll
        for (int r = 0; r < 4; ++r) {
#pragma unroll
            for (int off = 1; off < 16; off <<= 1) {
                RE[m][r] += __shfl_xor(RE[m][r], off);
                RP[m][r] += __shfl_xor(RP[m][r], off);
            }
        }
    if (c == 0) {
        // undo the diag poison injected into the positive-sums: exactly one
        // -50 per (m,r) row group in waves wy==wx of diag-containing blocks.
        if (g == (ti >> 2) && wy == wx) {
#pragma unroll
            for (int m = 0; m < 4; ++m)
#pragma unroll
                for (int r = 0; r < 4; ++r) RP[m][r] -= SELF_POISON;
        }
#pragma unroll
        for (int m = 0; m < 4; ++m)
#pragma unroll
            for (int r = 0; r < 4; ++r) {
                int gi = i0 + wy * 64 + m * 16 + quad * 4 + r;
                atomicAdd(&rowExp[gi], RE[m][r]);
                atomicAdd(&rowPos[gi], RP[m][r]);
            }
    }
}

// ---------------- finalize: loss = mean_i [ln(denom_i) - ln2*rowPos_i/cnt_i]
// Also builds the label histogram in LDS.
__global__ void finalize_kernel(const float* __restrict__ rowExp,
                                const float* __restrict__ rowPos,
                                const int* __restrict__ labels,
                                float* __restrict__ out) {
    __shared__ int hist[1024];
    __shared__ float ws16[16];
    int t = threadIdx.x;  // 1024 threads
    hist[t] = 0;
    __syncthreads();
    int lab[8];
#pragma unroll
    for (int k = 0; k < 8; ++k) {
        lab[k] = labels[t + 1024 * k];
        atomicAdd(&hist[lab[k]], 1);
    }
    __syncthreads();
    float a = 0.0f;
#pragma unroll
    for (int k = 0; k < 8; ++k) {
        int i = t + 1024 * k;
        int cnt = hist[lab[k]] - 1;
        if (cnt > 0)
            a += logf(rowExp[i] + 1e-9f) -
                 0.69314718056f * rowPos[i] / (float)cnt;
    }
#pragma unroll
    for (int off = 32; off > 0; off >>= 1) a += __shfl_xor(a, off);
    if ((t & 63) == 0) ws16[t >> 6] = a;
    __syncthreads();
    if (t == 0) {
        float s = 0.0f;
#pragma unroll
        for (int i = 0; i < 16; ++i) s += ws16[i];
        out[0] = s / (float)N;
    }
}

extern "C" void kernel_launch(void* const* d_in, const int* in_sizes, int n_in,
                              void* d_out, int out_size, void* d_ws, size_t ws_size,
                              hipStream_t stream) {
    const float* F      = (const float*)d_in[0];
    const int*   labels = (const int*)d_in[1];
    float* out = (float*)d_out;

    unsigned int* FbP = (unsigned int*)d_ws;            // N*D bf16 = 2 MB
    float* rowExp = (float*)((unsigned short*)d_ws + (size_t)N * D);  // N floats
    float* rowPos = rowExp + N;                          // N floats

    prep_kernel<<<N / 4, 256, 0, stream>>>(F, FbP, rowExp, rowPos);
    sim_kernel<<<64 * 16, 256, 0, stream>>>((const short8*)FbP, labels, rowExp,
                                            rowPos);
    finalize_kernel<<<1, 1024, 0, stream>>>(rowExp, rowPos, labels, out);
}